// Round 8
// baseline (283.713 us; speedup 1.0000x reference)
//
#include <hip/hip_runtime.h>
#include <hip/hip_bf16.h>
#include <math.h>

// ---------------------------------------------------------------------------
// DualHeadGAT R8: R6 aggregation kernels (proven fastest) + slim CSR build:
// no csr_dst (coef passes are wave-per-node), no cursor (atomicSub on deg),
// single-pass 2-barrier scan, int4 degree histogram, merged prefrag.
// bf16 feature gathers, MFMA GEMMs with fused att dots, implicit self-loops,
// deferred softmax normalization (exact). N=50000, IN=128, E=800000.
// ---------------------------------------------------------------------------

#define LRELU_SLOPE 0.2f

typedef __attribute__((ext_vector_type(8))) short short8;   // 8 bf16 = 4 VGPR
typedef __attribute__((ext_vector_type(4))) float f32x4;

__device__ inline ushort f2bf(float f) {            // RNE f32 -> bf16
    uint u = __float_as_uint(f);
    return (ushort)((u + 0x7FFFu + ((u >> 16) & 1u)) >> 16);
}
__device__ inline float bf2f(ushort u) {
    return __uint_as_float(((uint)u) << 16);
}

// ------- pre-fragment W[K][16J] (f32, row-major) into MFMA B-frag order ----
__device__ inline void prefrag_one(const float* __restrict__ W,
                                   ushort* __restrict__ out,
                                   int tid, int T, int ldn)
{
    int l = tid & 63, jt = tid >> 6;
    int t = jt % T, j = jt / T;
    int n = j * 16 + (l & 15);
    int k0 = t * 32 + (l >> 4) * 8;
    ushort o[8];
    #pragma unroll
    for (int b = 0; b < 8; ++b) o[b] = f2bf(W[(size_t)(k0 + b) * ldn + n]);
    *(short8*)(out + (size_t)tid * 8) = *(short8*)o;
}

__global__ __launch_bounds__(256)
void prefrag_both(const float* __restrict__ W1, const float* __restrict__ W2,
                  ushort* __restrict__ o1, ushort* __restrict__ o2)
{
    int tid = blockIdx.x * blockDim.x + threadIdx.x;
    if (tid < 16 * 4 * 64)             prefrag_one(W1, o1, tid, 4, 256);
    else if (tid < 16 * 4 * 64 + 4 * 8 * 64)
        prefrag_one(W2, o2, tid - 16 * 4 * 64, 8, 64);
}

// ---------------- MFMA GEMM, row-panel, LDS-free, bf16 output --------------
template<int J, int T, int H, bool AF32>
__global__ __launch_bounds__(256)
void gemm_mfma(const void* __restrict__ Araw, const ushort* __restrict__ Bf,
               ushort* __restrict__ Cbf, const float* __restrict__ attS,
               const float* __restrict__ attD, float* __restrict__ as_,
               float* __restrict__ ad_, int M)
{
    constexpr int K = 32 * T;
    constexpr int NN = 16 * J;
    const int l = threadIdx.x & 63;
    const int wid = blockIdx.x * (blockDim.x >> 6) + (threadIdx.x >> 6);
    const int base = wid * 16;
    if (base >= M) return;
    const int lm = l & 15, lg = l >> 4;

    short8 a[T];
    if constexpr (AF32) {
        const float* ap = (const float*)Araw + (size_t)(base + lm) * K + lg * 8;
        #pragma unroll
        for (int t = 0; t < T; ++t) {
            float4 v0 = *(const float4*)(ap + t * 32);
            float4 v1 = *(const float4*)(ap + t * 32 + 4);
            ushort o[8];
            o[0] = f2bf(v0.x); o[1] = f2bf(v0.y); o[2] = f2bf(v0.z); o[3] = f2bf(v0.w);
            o[4] = f2bf(v1.x); o[5] = f2bf(v1.y); o[6] = f2bf(v1.z); o[7] = f2bf(v1.w);
            a[t] = *(short8*)o;
        }
    } else {
        const ushort* ap = (const ushort*)Araw + (size_t)(base + lm) * K + lg * 8;
        #pragma unroll
        for (int t = 0; t < T; ++t) a[t] = *(const short8*)(ap + t * 32);
    }

    f32x4 acc[J];
    #pragma unroll
    for (int j = 0; j < J; ++j) acc[j] = (f32x4){0.f, 0.f, 0.f, 0.f};

    const ushort* bp = Bf + (size_t)l * 8;
    #pragma unroll
    for (int j = 0; j < J; ++j)
        #pragma unroll
        for (int t = 0; t < T; ++t) {
            short8 b = *(const short8*)(bp + (size_t)(j * T + t) * 512);
            acc[j] = __builtin_amdgcn_mfma_f32_16x16x32_bf16(a[t], b, acc[j], 0, 0, 0);
        }

    // epilogue: store bf16 C + fused attention dots (f32 precision)
    float sp[H][4], dp[H][4];
    #pragma unroll
    for (int h = 0; h < H; ++h)
        #pragma unroll
        for (int r = 0; r < 4; ++r) { sp[h][r] = 0.f; dp[h][r] = 0.f; }

    #pragma unroll
    for (int j = 0; j < J; ++j) {
        const int h = j / (J / H);
        const int coff = (j % (J / H)) * 16 + lm;     // col within head
        float ws = attS[h * 64 + coff];
        float wd = attD[h * 64 + coff];
        #pragma unroll
        for (int r = 0; r < 4; ++r) {
            int row = base + lg * 4 + r;
            Cbf[(size_t)row * NN + j * 16 + lm] = f2bf(acc[j][r]);
            sp[h][r] = fmaf(acc[j][r], ws, sp[h][r]);
            dp[h][r] = fmaf(acc[j][r], wd, dp[h][r]);
        }
    }
    #pragma unroll
    for (int h = 0; h < H; ++h)
        #pragma unroll
        for (int r = 0; r < 4; ++r) {
            float s = sp[h][r], d = dp[h][r];
            s += __shfl_xor(s, 1); d += __shfl_xor(d, 1);
            s += __shfl_xor(s, 2); d += __shfl_xor(d, 2);
            s += __shfl_xor(s, 4); d += __shfl_xor(d, 4);
            s += __shfl_xor(s, 8); d += __shfl_xor(d, 8);
            if (lm == 0) {
                int row = base + lg * 4 + r;
                as_[row * H + h] = s;
                ad_[row * H + h] = d;
            }
        }
}

// ---------------- CSR build (real edges only; self-loops implicit) ---------
__global__ __launch_bounds__(256)
void degree_hist(const int* __restrict__ edst, int* __restrict__ deg, int E)
{
    int i = (blockIdx.x * blockDim.x + threadIdx.x) << 2;
    if (i + 3 < E) {
        int4 v = *(const int4*)(edst + i);
        atomicAdd(&deg[v.x], 1); atomicAdd(&deg[v.y], 1);
        atomicAdd(&deg[v.z], 1); atomicAdd(&deg[v.w], 1);
    } else {
        for (; i < E; ++i) atomicAdd(&deg[edst[i]], 1);
    }
}

// single-block exclusive scan: 1024 threads, 52 contiguous elems/thread,
// 2 barriers total.
__global__ __launch_bounds__(1024)
void scan_rowptr(const int* __restrict__ deg, int* __restrict__ rowptr, int N)
{
    __shared__ int wsums[16];
    const int tid = threadIdx.x, lane = tid & 63, wid = tid >> 6;
    const int N4 = N >> 2;              // int4 count (N % 4 == 0)
    const int b4 = tid * 13;            // 13 int4 = 52 elems per thread
    int tsum = 0;
    #pragma unroll
    for (int k = 0; k < 13; ++k) {
        int i4 = b4 + k;
        if (i4 < N4) {
            int4 v = ((const int4*)deg)[i4];
            tsum += (v.x + v.y) + (v.z + v.w);
        }
    }
    int sc = tsum;                      // inclusive wave scan
    #pragma unroll
    for (int off = 1; off < 64; off <<= 1) {
        int t = __shfl_up(sc, off);
        if (lane >= off) sc += t;
    }
    if (lane == 63) wsums[wid] = sc;
    __syncthreads();
    if (wid == 0) {
        int wv = (lane < 16) ? wsums[lane] : 0;
        #pragma unroll
        for (int off = 1; off < 16; off <<= 1) {
            int t = __shfl_up(wv, off);
            if (lane >= off) wv += t;
        }
        if (lane < 16) wsums[lane] = wv;
    }
    __syncthreads();
    int run = (wid ? wsums[wid - 1] : 0) + sc - tsum;   // exclusive start
    #pragma unroll
    for (int k = 0; k < 13; ++k) {
        int i4 = b4 + k;
        if (i4 < N4) {
            int4 v = ((const int4*)deg)[i4];
            int4 o;
            o.x = run; o.y = run + v.x; o.z = o.y + v.y; o.w = o.z + v.z;
            ((int4*)rowptr)[i4] = o;
            run += (v.x + v.y) + (v.z + v.w);
        }
    }
    if (tid == 1023) rowptr[N] = run;   // all data precedes thread 1023
}

// scatter: claim slots by counting deg down (deg dead afterwards)
__global__ __launch_bounds__(256)
void scatter_edges(const int* __restrict__ esrc, const int* __restrict__ edst,
                   const int* __restrict__ rowptr, int* __restrict__ deg,
                   int* __restrict__ csr_src, int E)
{
    int i = blockIdx.x * blockDim.x + threadIdx.x;
    if (i >= E) return;
    int s = esrc[i], d = edst[i];
    int pos = rowptr[d] + atomicSub(&deg[d], 1) - 1;
    csr_src[pos] = s;
}

// ---- per-edge softmax coefficients, layer 1: wave per dst node ------------
// lane = slot*4 + head; p1 writes are fully coalesced.
__global__ __launch_bounds__(256)
void edge_coef_l1(const int* __restrict__ rowptr, const int* __restrict__ csr_src,
                  const float* __restrict__ as_, const float* __restrict__ ad_,
                  float* __restrict__ p1, int N)
{
    int w = (blockIdx.x * blockDim.x + threadIdx.x) >> 6;
    int lane = threadIdx.x & 63;
    if (w >= N) return;
    const int head = lane & 3;
    const int slot = lane >> 2;          // 0..15
    const float adv = ad_[w * 4 + head];
    const int e1 = rowptr[w + 1];
    for (int c = rowptr[w] + slot; c < e1; c += 16) {
        int s = csr_src[c];
        float e = as_[s * 4 + head] + adv;
        e = e > 0.f ? e : LRELU_SLOPE * e;
        p1[(size_t)c * 4 + head] = __expf(e);
    }
}

// ---- per-edge softmax coefficients, layer 2: wave per dst node ------------
__global__ __launch_bounds__(256)
void edge_coef_l2(const int* __restrict__ rowptr, const int* __restrict__ csr_src,
                  const float* __restrict__ as_, const float* __restrict__ ad_,
                  float* __restrict__ p2, int N)
{
    int w = (blockIdx.x * blockDim.x + threadIdx.x) >> 6;
    int lane = threadIdx.x & 63;
    if (w >= N) return;
    const float adv = ad_[w];
    const int e1 = rowptr[w + 1];
    for (int c = rowptr[w] + lane; c < e1; c += 64) {
        float e = as_[csr_src[c]] + adv;
        e = e > 0.f ? e : LRELU_SLOPE * e;
        p2[c] = __expf(e);
    }
}

// -------- layer-1 aggregation (R6 form): wave per dst; precomputed p -------
__global__ __launch_bounds__(256)
void aggregate_l1(const int* __restrict__ rowptr, const int* __restrict__ csr_src,
                  const float* __restrict__ p1, const ushort* __restrict__ h1,
                  const float* __restrict__ as_, const float* __restrict__ ad_,
                  const float* __restrict__ bias, ushort* __restrict__ outbf, int N)
{
    int w = (blockIdx.x * blockDim.x + threadIdx.x) >> 6;
    int lane = threadIdx.x & 63;
    if (w >= N) return;
    const int head = lane >> 4;          // 4 heads x 16 lanes
    const int c0 = lane << 2;            // ushort4 per lane
    float4 acc;
    float dsum;

    {   // implicit self-loop
        float el = as_[w * 4 + head] + ad_[w * 4 + head];
        el = el > 0.f ? el : LRELU_SLOPE * el;
        float p = __expf(el);
        ushort4 u = *(const ushort4*)(h1 + (size_t)w * 256 + c0);
        acc.x = p * bf2f(u.x); acc.y = p * bf2f(u.y);
        acc.z = p * bf2f(u.z); acc.w = p * bf2f(u.w);
        dsum = p;
    }

    int e = rowptr[w];
    const int e1 = rowptr[w + 1];
    for (; e + 3 < e1; e += 4) {         // 4x unroll for MLP
        int s0 = csr_src[e],     s1 = csr_src[e + 1];
        int s2 = csr_src[e + 2], s3 = csr_src[e + 3];
        float p0 = p1[(size_t)(e + 0) * 4 + head];
        float p1v = p1[(size_t)(e + 1) * 4 + head];
        float p2 = p1[(size_t)(e + 2) * 4 + head];
        float p3 = p1[(size_t)(e + 3) * 4 + head];
        ushort4 u0 = *(const ushort4*)(h1 + (size_t)s0 * 256 + c0);
        ushort4 u1 = *(const ushort4*)(h1 + (size_t)s1 * 256 + c0);
        ushort4 u2 = *(const ushort4*)(h1 + (size_t)s2 * 256 + c0);
        ushort4 u3 = *(const ushort4*)(h1 + (size_t)s3 * 256 + c0);
        acc.x = fmaf(p0, bf2f(u0.x), acc.x); acc.y = fmaf(p0, bf2f(u0.y), acc.y);
        acc.z = fmaf(p0, bf2f(u0.z), acc.z); acc.w = fmaf(p0, bf2f(u0.w), acc.w);
        acc.x = fmaf(p1v, bf2f(u1.x), acc.x); acc.y = fmaf(p1v, bf2f(u1.y), acc.y);
        acc.z = fmaf(p1v, bf2f(u1.z), acc.z); acc.w = fmaf(p1v, bf2f(u1.w), acc.w);
        acc.x = fmaf(p2, bf2f(u2.x), acc.x); acc.y = fmaf(p2, bf2f(u2.y), acc.y);
        acc.z = fmaf(p2, bf2f(u2.z), acc.z); acc.w = fmaf(p2, bf2f(u2.w), acc.w);
        acc.x = fmaf(p3, bf2f(u3.x), acc.x); acc.y = fmaf(p3, bf2f(u3.y), acc.y);
        acc.z = fmaf(p3, bf2f(u3.z), acc.z); acc.w = fmaf(p3, bf2f(u3.w), acc.w);
        dsum += (p0 + p1v) + (p2 + p3);
    }
    for (; e < e1; ++e) {
        int s0 = csr_src[e];
        float p0 = p1[(size_t)e * 4 + head];
        ushort4 u0 = *(const ushort4*)(h1 + (size_t)s0 * 256 + c0);
        acc.x = fmaf(p0, bf2f(u0.x), acc.x); acc.y = fmaf(p0, bf2f(u0.y), acc.y);
        acc.z = fmaf(p0, bf2f(u0.z), acc.z); acc.w = fmaf(p0, bf2f(u0.w), acc.w);
        dsum += p0;
    }
    const float inv = 1.f / (dsum + 1e-16f);
    const float4 b = *(const float4*)(bias + c0);
    float ox = acc.x * inv + b.x; ox = ox > 0.f ? ox : expm1f(ox);
    float oy = acc.y * inv + b.y; oy = oy > 0.f ? oy : expm1f(oy);
    float oz = acc.z * inv + b.z; oz = oz > 0.f ? oz : expm1f(oz);
    float ow = acc.w * inv + b.w; ow = ow > 0.f ? ow : expm1f(ow);
    ushort4 o;
    o.x = f2bf(ox); o.y = f2bf(oy); o.z = f2bf(oz); o.w = f2bf(ow);
    *(ushort4*)(outbf + (size_t)w * 256 + c0) = o;
}

// -------- layer-2 aggregation + scoring head (R6 form) ---------------------
__global__ __launch_bounds__(256)
void aggregate_l2(const int* __restrict__ rowptr, const int* __restrict__ csr_src,
                  const float* __restrict__ p2, const ushort* __restrict__ h2,
                  const float* __restrict__ as_, const float* __restrict__ ad_,
                  const float* __restrict__ b2, const float* __restrict__ Wsv,
                  const float* __restrict__ bs, float* __restrict__ hout,
                  float* __restrict__ scores, int N)
{
    int w = (blockIdx.x * blockDim.x + threadIdx.x) >> 6;
    int lane = threadIdx.x & 63;
    if (w >= N) return;
    float acc, dsum;
    {   // implicit self-loop
        float el = as_[w] + ad_[w];
        el = el > 0.f ? el : LRELU_SLOPE * el;
        float p = __expf(el);
        acc = p * bf2f(h2[(size_t)w * 64 + lane]);
        dsum = p;
    }
    int e = rowptr[w];
    const int e1 = rowptr[w + 1];
    for (; e + 3 < e1; e += 4) {
        int s0 = csr_src[e],     s1 = csr_src[e + 1];
        int s2 = csr_src[e + 2], s3 = csr_src[e + 3];
        float p0 = p2[e], p1 = p2[e + 1], p2v = p2[e + 2], p3 = p2[e + 3];
        acc = fmaf(p0, bf2f(h2[(size_t)s0 * 64 + lane]), acc);
        acc = fmaf(p1, bf2f(h2[(size_t)s1 * 64 + lane]), acc);
        acc = fmaf(p2v, bf2f(h2[(size_t)s2 * 64 + lane]), acc);
        acc = fmaf(p3, bf2f(h2[(size_t)s3 * 64 + lane]), acc);
        dsum += (p0 + p1) + (p2v + p3);
    }
    for (; e < e1; ++e) {
        int s0 = csr_src[e];
        float p0 = p2[e];
        acc = fmaf(p0, bf2f(h2[(size_t)s0 * 64 + lane]), acc);
        dsum += p0;
    }
    float v = acc / (dsum + 1e-16f) + b2[lane];
    v = v > 0.f ? v : expm1f(v);
    hout[(size_t)w * 64 + lane] = v;
    float sc = v * Wsv[lane];
    #pragma unroll
    for (int off = 32; off; off >>= 1) sc += __shfl_down(sc, off);
    if (lane == 0) scores[w] = sc + bs[0];
}

// ---------------------------------------------------------------------------
extern "C" void kernel_launch(void* const* d_in, const int* in_sizes, int n_in,
                              void* d_out, int out_size, void* d_ws, size_t ws_size,
                              hipStream_t stream)
{
    const float* x    = (const float*)d_in[0];
    const int*   ei   = (const int*)d_in[1];
    const float* W1   = (const float*)d_in[2];
    const float* as1w = (const float*)d_in[3];
    const float* ad1w = (const float*)d_in[4];
    const float* b1   = (const float*)d_in[5];
    const float* W2   = (const float*)d_in[6];
    const float* as2w = (const float*)d_in[7];
    const float* ad2w = (const float*)d_in[8];
    const float* b2   = (const float*)d_in[9];
    const float* Ws   = (const float*)d_in[10];
    const float* bs   = (const float*)d_in[11];

    const int N  = in_sizes[0] / 128;   // 50000
    const int E  = in_sizes[1] / 2;     // 800000
    const int* esrc = ei;
    const int* edst = ei + E;

    // ---- workspace layout (16B-aligned chunks) ----
    ushort* h1bf  = (ushort*)d_ws;                       // N*256 bf16
    ushort* hl1bf = h1bf + (size_t)N * 256;              // N*256 bf16
    ushort* h2bf  = hl1bf + (size_t)N * 256;             // N*64 bf16
    ushort* bfr1  = h2bf + (size_t)N * 64;               // 32768
    ushort* bfr2  = bfr1 + 32768;                        // 16384
    float*  as1   = (float*)(bfr2 + 16384);              // N*4
    float*  ad1   = as1 + (size_t)N * 4;                 // N*4
    float*  as2   = ad1 + (size_t)N * 4;                 // N
    float*  ad2   = as2 + N;                             // N
    float*  p1    = ad2 + N;                             // E*4
    float*  p2    = p1 + (size_t)E * 4;                  // E
    int*    deg    = (int*)(p2 + E);                     // N
    int*    rowptr = deg + N;                            // N+1 (+pad)
    int*    csr_src= rowptr + N + 4;                     // E

    float* hout   = (float*)d_out;                       // N*64
    float* scores = hout + (size_t)N * 64;               // N

    // ---------------- CSR build (shared by both layers) ----------------
    hipMemsetAsync(deg, 0, (size_t)N * sizeof(int), stream);
    degree_hist<<<(E / 4 + 255) / 256, 256, 0, stream>>>(edst, deg, E);
    scan_rowptr<<<1, 1024, 0, stream>>>(deg, rowptr, N);
    scatter_edges<<<(E + 255) / 256, 256, 0, stream>>>(
        esrc, edst, rowptr, deg, csr_src, E);

    // ---------------- weight pre-fragmentation (one launch) -------------
    prefrag_both<<<(16 * 4 * 64 + 4 * 8 * 64 + 255) / 256, 256, 0, stream>>>(
        W1, W2, bfr1, bfr2);

    // ---------------- layer 1 ----------------
    gemm_mfma<16, 4, 4, true><<<(N / 16 + 3) / 4, 256, 0, stream>>>(
        x, bfr1, h1bf, as1w, ad1w, as1, ad1, N);
    edge_coef_l1<<<((size_t)N * 64 + 255) / 256, 256, 0, stream>>>(
        rowptr, csr_src, as1, ad1, p1, N);
    aggregate_l1<<<((size_t)N * 64 + 255) / 256, 256, 0, stream>>>(
        rowptr, csr_src, p1, h1bf, as1, ad1, b1, hl1bf, N);

    // ---------------- layer 2 ----------------
    gemm_mfma<4, 8, 1, false><<<(N / 16 + 3) / 4, 256, 0, stream>>>(
        hl1bf, bfr2, h2bf, as2w, ad2w, as2, ad2, N);
    edge_coef_l2<<<((size_t)N * 64 + 255) / 256, 256, 0, stream>>>(
        rowptr, csr_src, as2, ad2, p2, N);
    aggregate_l2<<<((size_t)N * 64 + 255) / 256, 256, 0, stream>>>(
        rowptr, csr_src, p2, h2bf, as2, ad2, b2, Ws, bs, hout, scores, N);
}

// Round 9
// 266.698 us; speedup vs baseline: 1.0638x; 1.0638x over previous
//
#include <hip/hip_runtime.h>
#include <hip/hip_bf16.h>
#include <math.h>

// ---------------------------------------------------------------------------
// DualHeadGAT R9: best-of composition.
//  - R4 aggregation kernels (inline exp, 4x unroll, max MLP) — p-precompute
//    passes removed (R6/R8 showed they cost more wall time than they save).
//  - R8 slim CSR build: int4 degree hist, single-pass 2-barrier scan,
//    atomicSub slot claim (no cursor array).
//  - R6 gemm1: f32 A converted to bf16 in-register (no conv_bf16 pass).
//  - merged prefrag; 9 kernel launches total.
// bf16 feature gathers, MFMA GEMMs with fused att dots, implicit self-loops,
// deferred softmax normalization (exact). N=50000, IN=128, E=800000.
// ---------------------------------------------------------------------------

#define LRELU_SLOPE 0.2f

typedef __attribute__((ext_vector_type(8))) short short8;   // 8 bf16 = 4 VGPR
typedef __attribute__((ext_vector_type(4))) float f32x4;

__device__ inline ushort f2bf(float f) {            // RNE f32 -> bf16
    uint u = __float_as_uint(f);
    return (ushort)((u + 0x7FFFu + ((u >> 16) & 1u)) >> 16);
}
__device__ inline float bf2f(ushort u) {
    return __uint_as_float(((uint)u) << 16);
}

// ------- pre-fragment W[K][16J] (f32, row-major) into MFMA B-frag order ----
__device__ inline void prefrag_one(const float* __restrict__ W,
                                   ushort* __restrict__ out,
                                   int tid, int T, int ldn)
{
    int l = tid & 63, jt = tid >> 6;
    int t = jt % T, j = jt / T;
    int n = j * 16 + (l & 15);
    int k0 = t * 32 + (l >> 4) * 8;
    ushort o[8];
    #pragma unroll
    for (int b = 0; b < 8; ++b) o[b] = f2bf(W[(size_t)(k0 + b) * ldn + n]);
    *(short8*)(out + (size_t)tid * 8) = *(short8*)o;
}

__global__ __launch_bounds__(256)
void prefrag_both(const float* __restrict__ W1, const float* __restrict__ W2,
                  ushort* __restrict__ o1, ushort* __restrict__ o2)
{
    int tid = blockIdx.x * blockDim.x + threadIdx.x;
    if (tid < 16 * 4 * 64)             prefrag_one(W1, o1, tid, 4, 256);
    else if (tid < 16 * 4 * 64 + 4 * 8 * 64)
        prefrag_one(W2, o2, tid - 16 * 4 * 64, 8, 64);
}

// ---------------- MFMA GEMM, row-panel, LDS-free, bf16 output --------------
template<int J, int T, int H, bool AF32>
__global__ __launch_bounds__(256)
void gemm_mfma(const void* __restrict__ Araw, const ushort* __restrict__ Bf,
               ushort* __restrict__ Cbf, const float* __restrict__ attS,
               const float* __restrict__ attD, float* __restrict__ as_,
               float* __restrict__ ad_, int M)
{
    constexpr int K = 32 * T;
    constexpr int NN = 16 * J;
    const int l = threadIdx.x & 63;
    const int wid = blockIdx.x * (blockDim.x >> 6) + (threadIdx.x >> 6);
    const int base = wid * 16;
    if (base >= M) return;
    const int lm = l & 15, lg = l >> 4;

    short8 a[T];
    if constexpr (AF32) {
        const float* ap = (const float*)Araw + (size_t)(base + lm) * K + lg * 8;
        #pragma unroll
        for (int t = 0; t < T; ++t) {
            float4 v0 = *(const float4*)(ap + t * 32);
            float4 v1 = *(const float4*)(ap + t * 32 + 4);
            ushort o[8];
            o[0] = f2bf(v0.x); o[1] = f2bf(v0.y); o[2] = f2bf(v0.z); o[3] = f2bf(v0.w);
            o[4] = f2bf(v1.x); o[5] = f2bf(v1.y); o[6] = f2bf(v1.z); o[7] = f2bf(v1.w);
            a[t] = *(short8*)o;
        }
    } else {
        const ushort* ap = (const ushort*)Araw + (size_t)(base + lm) * K + lg * 8;
        #pragma unroll
        for (int t = 0; t < T; ++t) a[t] = *(const short8*)(ap + t * 32);
    }

    f32x4 acc[J];
    #pragma unroll
    for (int j = 0; j < J; ++j) acc[j] = (f32x4){0.f, 0.f, 0.f, 0.f};

    const ushort* bp = Bf + (size_t)l * 8;
    #pragma unroll
    for (int j = 0; j < J; ++j)
        #pragma unroll
        for (int t = 0; t < T; ++t) {
            short8 b = *(const short8*)(bp + (size_t)(j * T + t) * 512);
            acc[j] = __builtin_amdgcn_mfma_f32_16x16x32_bf16(a[t], b, acc[j], 0, 0, 0);
        }

    // epilogue: store bf16 C + fused attention dots (f32 precision)
    float sp[H][4], dp[H][4];
    #pragma unroll
    for (int h = 0; h < H; ++h)
        #pragma unroll
        for (int r = 0; r < 4; ++r) { sp[h][r] = 0.f; dp[h][r] = 0.f; }

    #pragma unroll
    for (int j = 0; j < J; ++j) {
        const int h = j / (J / H);
        const int coff = (j % (J / H)) * 16 + lm;     // col within head
        float ws = attS[h * 64 + coff];
        float wd = attD[h * 64 + coff];
        #pragma unroll
        for (int r = 0; r < 4; ++r) {
            int row = base + lg * 4 + r;
            Cbf[(size_t)row * NN + j * 16 + lm] = f2bf(acc[j][r]);
            sp[h][r] = fmaf(acc[j][r], ws, sp[h][r]);
            dp[h][r] = fmaf(acc[j][r], wd, dp[h][r]);
        }
    }
    #pragma unroll
    for (int h = 0; h < H; ++h)
        #pragma unroll
        for (int r = 0; r < 4; ++r) {
            float s = sp[h][r], d = dp[h][r];
            s += __shfl_xor(s, 1); d += __shfl_xor(d, 1);
            s += __shfl_xor(s, 2); d += __shfl_xor(d, 2);
            s += __shfl_xor(s, 4); d += __shfl_xor(d, 4);
            s += __shfl_xor(s, 8); d += __shfl_xor(d, 8);
            if (lm == 0) {
                int row = base + lg * 4 + r;
                as_[row * H + h] = s;
                ad_[row * H + h] = d;
            }
        }
}

// ---------------- CSR build (real edges only; self-loops implicit) ---------
__global__ __launch_bounds__(256)
void degree_hist(const int* __restrict__ edst, int* __restrict__ deg, int E)
{
    int i = (blockIdx.x * blockDim.x + threadIdx.x) << 2;
    if (i + 3 < E) {
        int4 v = *(const int4*)(edst + i);
        atomicAdd(&deg[v.x], 1); atomicAdd(&deg[v.y], 1);
        atomicAdd(&deg[v.z], 1); atomicAdd(&deg[v.w], 1);
    } else {
        for (; i < E; ++i) atomicAdd(&deg[edst[i]], 1);
    }
}

// single-block exclusive scan: 1024 threads, 52 contiguous elems/thread,
// 2 barriers total.
__global__ __launch_bounds__(1024)
void scan_rowptr(const int* __restrict__ deg, int* __restrict__ rowptr, int N)
{
    __shared__ int wsums[16];
    const int tid = threadIdx.x, lane = tid & 63, wid = tid >> 6;
    const int N4 = N >> 2;              // int4 count (N % 4 == 0)
    const int b4 = tid * 13;            // 13 int4 = 52 elems per thread
    int tsum = 0;
    #pragma unroll
    for (int k = 0; k < 13; ++k) {
        int i4 = b4 + k;
        if (i4 < N4) {
            int4 v = ((const int4*)deg)[i4];
            tsum += (v.x + v.y) + (v.z + v.w);
        }
    }
    int sc = tsum;                      // inclusive wave scan
    #pragma unroll
    for (int off = 1; off < 64; off <<= 1) {
        int t = __shfl_up(sc, off);
        if (lane >= off) sc += t;
    }
    if (lane == 63) wsums[wid] = sc;
    __syncthreads();
    if (wid == 0) {
        int wv = (lane < 16) ? wsums[lane] : 0;
        #pragma unroll
        for (int off = 1; off < 16; off <<= 1) {
            int t = __shfl_up(wv, off);
            if (lane >= off) wv += t;
        }
        if (lane < 16) wsums[lane] = wv;
    }
    __syncthreads();
    int run = (wid ? wsums[wid - 1] : 0) + sc - tsum;   // exclusive start
    #pragma unroll
    for (int k = 0; k < 13; ++k) {
        int i4 = b4 + k;
        if (i4 < N4) {
            int4 v = ((const int4*)deg)[i4];
            int4 o;
            o.x = run; o.y = run + v.x; o.z = o.y + v.y; o.w = o.z + v.z;
            ((int4*)rowptr)[i4] = o;
            run += (v.x + v.y) + (v.z + v.w);
        }
    }
    if (tid == 1023) rowptr[N] = run;   // all data precedes thread 1023
}

// scatter: claim slots by counting deg down (deg dead afterwards)
__global__ __launch_bounds__(256)
void scatter_edges(const int* __restrict__ esrc, const int* __restrict__ edst,
                   const int* __restrict__ rowptr, int* __restrict__ deg,
                   int* __restrict__ csr_src, int E)
{
    int i = blockIdx.x * blockDim.x + threadIdx.x;
    if (i >= E) return;
    int s = esrc[i], d = edst[i];
    int pos = rowptr[d] + atomicSub(&deg[d], 1) - 1;
    csr_src[pos] = s;
}

// -------- layer-1 aggregation (R4 form): wave per dst; inline exp ----------
__global__ __launch_bounds__(256)
void aggregate_l1(const int* __restrict__ rowptr, const int* __restrict__ csr_src,
                  const ushort* __restrict__ h1, const float* __restrict__ as_,
                  const float* __restrict__ ad_, const float* __restrict__ bias,
                  ushort* __restrict__ outbf, int N)
{
    int w = (blockIdx.x * blockDim.x + threadIdx.x) >> 6;
    int lane = threadIdx.x & 63;
    if (w >= N) return;
    const int head = lane >> 4;          // 4 heads x 16 lanes
    const int c0 = lane << 2;            // ushort4 per lane
    const float ad = ad_[w * 4 + head];
    float4 acc;
    float dsum;

    {   // implicit self-loop
        float el = as_[w * 4 + head] + ad;
        el = el > 0.f ? el : LRELU_SLOPE * el;
        float p = __expf(el);
        ushort4 u = *(const ushort4*)(h1 + (size_t)w * 256 + c0);
        acc.x = p * bf2f(u.x); acc.y = p * bf2f(u.y);
        acc.z = p * bf2f(u.z); acc.w = p * bf2f(u.w);
        dsum = p;
    }

    int e = rowptr[w];
    const int e1 = rowptr[w + 1];
    for (; e + 3 < e1; e += 4) {         // 4x unroll for MLP
        int s0 = csr_src[e], s1 = csr_src[e + 1];
        int s2 = csr_src[e + 2], s3 = csr_src[e + 3];
        float e0 = as_[s0 * 4 + head] + ad, e1v = as_[s1 * 4 + head] + ad;
        float e2 = as_[s2 * 4 + head] + ad, e3 = as_[s3 * 4 + head] + ad;
        e0 = e0 > 0.f ? e0 : LRELU_SLOPE * e0;
        e1v = e1v > 0.f ? e1v : LRELU_SLOPE * e1v;
        e2 = e2 > 0.f ? e2 : LRELU_SLOPE * e2;
        e3 = e3 > 0.f ? e3 : LRELU_SLOPE * e3;
        float p0 = __expf(e0), p1 = __expf(e1v);
        float p2 = __expf(e2), p3 = __expf(e3);
        ushort4 u0 = *(const ushort4*)(h1 + (size_t)s0 * 256 + c0);
        ushort4 u1 = *(const ushort4*)(h1 + (size_t)s1 * 256 + c0);
        ushort4 u2 = *(const ushort4*)(h1 + (size_t)s2 * 256 + c0);
        ushort4 u3 = *(const ushort4*)(h1 + (size_t)s3 * 256 + c0);
        acc.x = fmaf(p0, bf2f(u0.x), acc.x); acc.y = fmaf(p0, bf2f(u0.y), acc.y);
        acc.z = fmaf(p0, bf2f(u0.z), acc.z); acc.w = fmaf(p0, bf2f(u0.w), acc.w);
        acc.x = fmaf(p1, bf2f(u1.x), acc.x); acc.y = fmaf(p1, bf2f(u1.y), acc.y);
        acc.z = fmaf(p1, bf2f(u1.z), acc.z); acc.w = fmaf(p1, bf2f(u1.w), acc.w);
        acc.x = fmaf(p2, bf2f(u2.x), acc.x); acc.y = fmaf(p2, bf2f(u2.y), acc.y);
        acc.z = fmaf(p2, bf2f(u2.z), acc.z); acc.w = fmaf(p2, bf2f(u2.w), acc.w);
        acc.x = fmaf(p3, bf2f(u3.x), acc.x); acc.y = fmaf(p3, bf2f(u3.y), acc.y);
        acc.z = fmaf(p3, bf2f(u3.z), acc.z); acc.w = fmaf(p3, bf2f(u3.w), acc.w);
        dsum += (p0 + p1) + (p2 + p3);
    }
    for (; e < e1; ++e) {
        int s0 = csr_src[e];
        float e0 = as_[s0 * 4 + head] + ad;
        e0 = e0 > 0.f ? e0 : LRELU_SLOPE * e0;
        float p0 = __expf(e0);
        ushort4 u0 = *(const ushort4*)(h1 + (size_t)s0 * 256 + c0);
        acc.x = fmaf(p0, bf2f(u0.x), acc.x); acc.y = fmaf(p0, bf2f(u0.y), acc.y);
        acc.z = fmaf(p0, bf2f(u0.z), acc.z); acc.w = fmaf(p0, bf2f(u0.w), acc.w);
        dsum += p0;
    }
    const float inv = 1.f / (dsum + 1e-16f);
    const float4 b = *(const float4*)(bias + c0);
    float ox = acc.x * inv + b.x; ox = ox > 0.f ? ox : expm1f(ox);
    float oy = acc.y * inv + b.y; oy = oy > 0.f ? oy : expm1f(oy);
    float oz = acc.z * inv + b.z; oz = oz > 0.f ? oz : expm1f(oz);
    float ow = acc.w * inv + b.w; ow = ow > 0.f ? ow : expm1f(ow);
    ushort4 o;
    o.x = f2bf(ox); o.y = f2bf(oy); o.z = f2bf(oz); o.w = f2bf(ow);
    *(ushort4*)(outbf + (size_t)w * 256 + c0) = o;
}

// -------- layer-2 aggregation + scoring head (R4 form) ---------------------
__global__ __launch_bounds__(256)
void aggregate_l2(const int* __restrict__ rowptr, const int* __restrict__ csr_src,
                  const ushort* __restrict__ h2, const float* __restrict__ as_,
                  const float* __restrict__ ad_, const float* __restrict__ b2,
                  const float* __restrict__ Wsv, const float* __restrict__ bs,
                  float* __restrict__ hout, float* __restrict__ scores, int N)
{
    int w = (blockIdx.x * blockDim.x + threadIdx.x) >> 6;
    int lane = threadIdx.x & 63;
    if (w >= N) return;
    const float ad = ad_[w];
    float acc, dsum;
    {   // implicit self-loop
        float el = as_[w] + ad;
        el = el > 0.f ? el : LRELU_SLOPE * el;
        float p = __expf(el);
        acc = p * bf2f(h2[(size_t)w * 64 + lane]);
        dsum = p;
    }
    int e = rowptr[w];
    const int e1 = rowptr[w + 1];
    for (; e + 3 < e1; e += 4) {
        int s0 = csr_src[e], s1 = csr_src[e + 1];
        int s2 = csr_src[e + 2], s3 = csr_src[e + 3];
        float e0 = as_[s0] + ad, e1v = as_[s1] + ad;
        float e2 = as_[s2] + ad, e3 = as_[s3] + ad;
        e0 = e0 > 0.f ? e0 : LRELU_SLOPE * e0;
        e1v = e1v > 0.f ? e1v : LRELU_SLOPE * e1v;
        e2 = e2 > 0.f ? e2 : LRELU_SLOPE * e2;
        e3 = e3 > 0.f ? e3 : LRELU_SLOPE * e3;
        float p0 = __expf(e0), p1 = __expf(e1v);
        float p2 = __expf(e2), p3 = __expf(e3);
        acc = fmaf(p0, bf2f(h2[(size_t)s0 * 64 + lane]), acc);
        acc = fmaf(p1, bf2f(h2[(size_t)s1 * 64 + lane]), acc);
        acc = fmaf(p2, bf2f(h2[(size_t)s2 * 64 + lane]), acc);
        acc = fmaf(p3, bf2f(h2[(size_t)s3 * 64 + lane]), acc);
        dsum += (p0 + p1) + (p2 + p3);
    }
    for (; e < e1; ++e) {
        int s0 = csr_src[e];
        float e0 = as_[s0] + ad;
        e0 = e0 > 0.f ? e0 : LRELU_SLOPE * e0;
        float p0 = __expf(e0);
        acc = fmaf(p0, bf2f(h2[(size_t)s0 * 64 + lane]), acc);
        dsum += p0;
    }
    float v = acc / (dsum + 1e-16f) + b2[lane];
    v = v > 0.f ? v : expm1f(v);
    hout[(size_t)w * 64 + lane] = v;
    float sc = v * Wsv[lane];
    #pragma unroll
    for (int off = 32; off; off >>= 1) sc += __shfl_down(sc, off);
    if (lane == 0) scores[w] = sc + bs[0];
}

// ---------------------------------------------------------------------------
extern "C" void kernel_launch(void* const* d_in, const int* in_sizes, int n_in,
                              void* d_out, int out_size, void* d_ws, size_t ws_size,
                              hipStream_t stream)
{
    const float* x    = (const float*)d_in[0];
    const int*   ei   = (const int*)d_in[1];
    const float* W1   = (const float*)d_in[2];
    const float* as1w = (const float*)d_in[3];
    const float* ad1w = (const float*)d_in[4];
    const float* b1   = (const float*)d_in[5];
    const float* W2   = (const float*)d_in[6];
    const float* as2w = (const float*)d_in[7];
    const float* ad2w = (const float*)d_in[8];
    const float* b2   = (const float*)d_in[9];
    const float* Ws   = (const float*)d_in[10];
    const float* bs   = (const float*)d_in[11];

    const int N  = in_sizes[0] / 128;   // 50000
    const int E  = in_sizes[1] / 2;     // 800000
    const int* esrc = ei;
    const int* edst = ei + E;

    // ---- workspace layout (16B-aligned chunks) ----
    ushort* h1bf  = (ushort*)d_ws;                       // N*256 bf16
    ushort* hl1bf = h1bf + (size_t)N * 256;              // N*256 bf16
    ushort* h2bf  = hl1bf + (size_t)N * 256;             // N*64 bf16
    ushort* bfr1  = h2bf + (size_t)N * 64;               // 32768
    ushort* bfr2  = bfr1 + 32768;                        // 16384
    float*  as1   = (float*)(bfr2 + 16384);              // N*4
    float*  ad1   = as1 + (size_t)N * 4;                 // N*4
    float*  as2   = ad1 + (size_t)N * 4;                 // N
    float*  ad2   = as2 + N;                             // N
    int*    deg    = (int*)(ad2 + N);                    // N
    int*    rowptr = deg + N;                            // N+1 (+pad)
    int*    csr_src= rowptr + N + 4;                     // E

    float* hout   = (float*)d_out;                       // N*64
    float* scores = hout + (size_t)N * 64;               // N

    // ---------------- CSR build (shared by both layers) ----------------
    hipMemsetAsync(deg, 0, (size_t)N * sizeof(int), stream);
    degree_hist<<<(E / 4 + 255) / 256, 256, 0, stream>>>(edst, deg, E);
    scan_rowptr<<<1, 1024, 0, stream>>>(deg, rowptr, N);
    scatter_edges<<<(E + 255) / 256, 256, 0, stream>>>(
        esrc, edst, rowptr, deg, csr_src, E);

    // ---------------- weight pre-fragmentation (one launch) -------------
    prefrag_both<<<(16 * 4 * 64 + 4 * 8 * 64 + 255) / 256, 256, 0, stream>>>(
        W1, W2, bfr1, bfr2);

    // ---------------- layer 1 ----------------
    gemm_mfma<16, 4, 4, true><<<(N / 16 + 3) / 4, 256, 0, stream>>>(
        x, bfr1, h1bf, as1w, ad1w, as1, ad1, N);
    aggregate_l1<<<((size_t)N * 64 + 255) / 256, 256, 0, stream>>>(
        rowptr, csr_src, h1bf, as1, ad1, b1, hl1bf, N);

    // ---------------- layer 2 ----------------
    gemm_mfma<4, 8, 1, false><<<(N / 16 + 3) / 4, 256, 0, stream>>>(
        hl1bf, bfr2, h2bf, as2w, ad2w, as2, ad2, N);
    aggregate_l2<<<((size_t)N * 64 + 255) / 256, 256, 0, stream>>>(
        rowptr, csr_src, h2bf, as2, ad2, b2, Ws, bs, hout, scores, N);
}

// Round 10
// 263.693 us; speedup vs baseline: 1.0759x; 1.0114x over previous
//
#include <hip/hip_runtime.h>
#include <hip/hip_bf16.h>
#include <math.h>

// ---------------------------------------------------------------------------
// DualHeadGAT R10:
//  - split conv_bf16 restored (R4-proven; fused f32-A gemm1 cost ~10 us in
//    R6/R9), merged with prefrag into one `prep` launch.
//  - aggregates: 8x edge unroll (8 gathers in flight; was 4).
//  - R8 slim CSR: int4 hist, 2-barrier scan, atomicSub slot claim.
//  - bf16 feature gathers, MFMA GEMMs with fused att dots, implicit
//    self-loops, deferred softmax normalization (exact).
// N=50000, IN=128, E=800000. f32 in/out, int32 edges. 9 launches.
// ---------------------------------------------------------------------------

#define LRELU_SLOPE 0.2f

typedef __attribute__((ext_vector_type(8))) short short8;   // 8 bf16 = 4 VGPR
typedef __attribute__((ext_vector_type(4))) float f32x4;

__device__ inline ushort f2bf(float f) {            // RNE f32 -> bf16
    uint u = __float_as_uint(f);
    return (ushort)((u + 0x7FFFu + ((u >> 16) & 1u)) >> 16);
}
__device__ inline float bf2f(ushort u) {
    return __uint_as_float(((uint)u) << 16);
}

// ------- pre-fragment W[K][16J] (f32, row-major) into MFMA B-frag order ----
__device__ inline void prefrag_one(const float* __restrict__ W,
                                   ushort* __restrict__ out,
                                   int tid, int T, int ldn)
{
    int l = tid & 63, jt = tid >> 6;
    int t = jt % T, j = jt / T;
    int n = j * 16 + (l & 15);
    int k0 = t * 32 + (l >> 4) * 8;
    ushort o[8];
    #pragma unroll
    for (int b = 0; b < 8; ++b) o[b] = f2bf(W[(size_t)(k0 + b) * ldn + n]);
    *(short8*)(out + (size_t)tid * 8) = *(short8*)o;
}

// ---- prep: x f32->bf16 (4/thread) + both weight prefrags, one launch ------
__global__ __launch_bounds__(256)
void prep(const float* __restrict__ x, ushort* __restrict__ xbf,
          const float* __restrict__ W1, const float* __restrict__ W2,
          ushort* __restrict__ o1, ushort* __restrict__ o2, int nconv4)
{
    int tid = blockIdx.x * blockDim.x + threadIdx.x;
    if (tid < nconv4) {
        int i = tid << 2;
        float4 v = *(const float4*)(x + i);
        ushort4 o;
        o.x = f2bf(v.x); o.y = f2bf(v.y); o.z = f2bf(v.z); o.w = f2bf(v.w);
        *(ushort4*)(xbf + i) = o;
        return;
    }
    int t = tid - nconv4;
    if (t < 16 * 4 * 64)                 prefrag_one(W1, o1, t, 4, 256);
    else if (t < 16 * 4 * 64 + 4 * 8 * 64)
        prefrag_one(W2, o2, t - 16 * 4 * 64, 8, 64);
}

// ---------------- MFMA GEMM, row-panel, LDS-free, bf16 in/out --------------
template<int J, int T, int H>
__global__ __launch_bounds__(256)
void gemm_mfma(const ushort* __restrict__ A, const ushort* __restrict__ Bf,
               ushort* __restrict__ Cbf, const float* __restrict__ attS,
               const float* __restrict__ attD, float* __restrict__ as_,
               float* __restrict__ ad_, int M)
{
    constexpr int K = 32 * T;
    constexpr int NN = 16 * J;
    const int l = threadIdx.x & 63;
    const int wid = blockIdx.x * (blockDim.x >> 6) + (threadIdx.x >> 6);
    const int base = wid * 16;
    if (base >= M) return;
    const int lm = l & 15, lg = l >> 4;

    short8 a[T];
    const ushort* ap = A + (size_t)(base + lm) * K + lg * 8;
    #pragma unroll
    for (int t = 0; t < T; ++t) a[t] = *(const short8*)(ap + t * 32);

    f32x4 acc[J];
    #pragma unroll
    for (int j = 0; j < J; ++j) acc[j] = (f32x4){0.f, 0.f, 0.f, 0.f};

    const ushort* bp = Bf + (size_t)l * 8;
    #pragma unroll
    for (int j = 0; j < J; ++j)
        #pragma unroll
        for (int t = 0; t < T; ++t) {
            short8 b = *(const short8*)(bp + (size_t)(j * T + t) * 512);
            acc[j] = __builtin_amdgcn_mfma_f32_16x16x32_bf16(a[t], b, acc[j], 0, 0, 0);
        }

    // epilogue: store bf16 C + fused attention dots (f32 precision)
    float sp[H][4], dp[H][4];
    #pragma unroll
    for (int h = 0; h < H; ++h)
        #pragma unroll
        for (int r = 0; r < 4; ++r) { sp[h][r] = 0.f; dp[h][r] = 0.f; }

    #pragma unroll
    for (int j = 0; j < J; ++j) {
        const int h = j / (J / H);
        const int coff = (j % (J / H)) * 16 + lm;     // col within head
        float ws = attS[h * 64 + coff];
        float wd = attD[h * 64 + coff];
        #pragma unroll
        for (int r = 0; r < 4; ++r) {
            int row = base + lg * 4 + r;
            Cbf[(size_t)row * NN + j * 16 + lm] = f2bf(acc[j][r]);
            sp[h][r] = fmaf(acc[j][r], ws, sp[h][r]);
            dp[h][r] = fmaf(acc[j][r], wd, dp[h][r]);
        }
    }
    #pragma unroll
    for (int h = 0; h < H; ++h)
        #pragma unroll
        for (int r = 0; r < 4; ++r) {
            float s = sp[h][r], d = dp[h][r];
            s += __shfl_xor(s, 1); d += __shfl_xor(d, 1);
            s += __shfl_xor(s, 2); d += __shfl_xor(d, 2);
            s += __shfl_xor(s, 4); d += __shfl_xor(d, 4);
            s += __shfl_xor(s, 8); d += __shfl_xor(d, 8);
            if (lm == 0) {
                int row = base + lg * 4 + r;
                as_[row * H + h] = s;
                ad_[row * H + h] = d;
            }
        }
}

// ---------------- CSR build (real edges only; self-loops implicit) ---------
__global__ __launch_bounds__(256)
void degree_hist(const int* __restrict__ edst, int* __restrict__ deg, int E)
{
    int i = (blockIdx.x * blockDim.x + threadIdx.x) << 2;
    if (i + 3 < E) {
        int4 v = *(const int4*)(edst + i);
        atomicAdd(&deg[v.x], 1); atomicAdd(&deg[v.y], 1);
        atomicAdd(&deg[v.z], 1); atomicAdd(&deg[v.w], 1);
    } else {
        for (; i < E; ++i) atomicAdd(&deg[edst[i]], 1);
    }
}

// single-block exclusive scan: 1024 threads, 52 contiguous elems/thread,
// 2 barriers total.
__global__ __launch_bounds__(1024)
void scan_rowptr(const int* __restrict__ deg, int* __restrict__ rowptr, int N)
{
    __shared__ int wsums[16];
    const int tid = threadIdx.x, lane = tid & 63, wid = tid >> 6;
    const int N4 = N >> 2;              // int4 count (N % 4 == 0)
    const int b4 = tid * 13;            // 13 int4 = 52 elems per thread
    int tsum = 0;
    #pragma unroll
    for (int k = 0; k < 13; ++k) {
        int i4 = b4 + k;
        if (i4 < N4) {
            int4 v = ((const int4*)deg)[i4];
            tsum += (v.x + v.y) + (v.z + v.w);
        }
    }
    int sc = tsum;                      // inclusive wave scan
    #pragma unroll
    for (int off = 1; off < 64; off <<= 1) {
        int t = __shfl_up(sc, off);
        if (lane >= off) sc += t;
    }
    if (lane == 63) wsums[wid] = sc;
    __syncthreads();
    if (wid == 0) {
        int wv = (lane < 16) ? wsums[lane] : 0;
        #pragma unroll
        for (int off = 1; off < 16; off <<= 1) {
            int t = __shfl_up(wv, off);
            if (lane >= off) wv += t;
        }
        if (lane < 16) wsums[lane] = wv;
    }
    __syncthreads();
    int run = (wid ? wsums[wid - 1] : 0) + sc - tsum;   // exclusive start
    #pragma unroll
    for (int k = 0; k < 13; ++k) {
        int i4 = b4 + k;
        if (i4 < N4) {
            int4 v = ((const int4*)deg)[i4];
            int4 o;
            o.x = run; o.y = run + v.x; o.z = o.y + v.y; o.w = o.z + v.z;
            ((int4*)rowptr)[i4] = o;
            run += (v.x + v.y) + (v.z + v.w);
        }
    }
    if (tid == 1023) rowptr[N] = run;   // all data precedes thread 1023
}

// scatter: claim slots by counting deg down (deg returns to 0 afterwards)
__global__ __launch_bounds__(256)
void scatter_edges(const int* __restrict__ esrc, const int* __restrict__ edst,
                   const int* __restrict__ rowptr, int* __restrict__ deg,
                   int* __restrict__ csr_src, int E)
{
    int i = blockIdx.x * blockDim.x + threadIdx.x;
    if (i >= E) return;
    int s = esrc[i], d = edst[i];
    int pos = rowptr[d] + atomicSub(&deg[d], 1) - 1;
    csr_src[pos] = s;
}

// -------- layer-1 aggregation: wave per dst; inline exp; 8x unroll ---------
__global__ __launch_bounds__(256)
void aggregate_l1(const int* __restrict__ rowptr, const int* __restrict__ csr_src,
                  const ushort* __restrict__ h1, const float* __restrict__ as_,
                  const float* __restrict__ ad_, const float* __restrict__ bias,
                  ushort* __restrict__ outbf, int N)
{
    int w = (blockIdx.x * blockDim.x + threadIdx.x) >> 6;
    int lane = threadIdx.x & 63;
    if (w >= N) return;
    const int head = lane >> 4;          // 4 heads x 16 lanes
    const int c0 = lane << 2;            // ushort4 per lane
    const float ad = ad_[w * 4 + head];
    float4 acc;
    float dsum;

    {   // implicit self-loop
        float el = as_[w * 4 + head] + ad;
        el = el > 0.f ? el : LRELU_SLOPE * el;
        float p = __expf(el);
        ushort4 u = *(const ushort4*)(h1 + (size_t)w * 256 + c0);
        acc.x = p * bf2f(u.x); acc.y = p * bf2f(u.y);
        acc.z = p * bf2f(u.z); acc.w = p * bf2f(u.w);
        dsum = p;
    }

    int e = rowptr[w];
    const int e1 = rowptr[w + 1];
    for (; e + 7 < e1; e += 8) {         // 8 gathers in flight
        int s_[8];
        #pragma unroll
        for (int u = 0; u < 8; ++u) s_[u] = csr_src[e + u];
        float p_[8];
        #pragma unroll
        for (int u = 0; u < 8; ++u) {
            float ev = as_[s_[u] * 4 + head] + ad;
            ev = ev > 0.f ? ev : LRELU_SLOPE * ev;
            p_[u] = __expf(ev);
        }
        ushort4 f_[8];
        #pragma unroll
        for (int u = 0; u < 8; ++u)
            f_[u] = *(const ushort4*)(h1 + (size_t)s_[u] * 256 + c0);
        #pragma unroll
        for (int u = 0; u < 8; ++u) {
            acc.x = fmaf(p_[u], bf2f(f_[u].x), acc.x);
            acc.y = fmaf(p_[u], bf2f(f_[u].y), acc.y);
            acc.z = fmaf(p_[u], bf2f(f_[u].z), acc.z);
            acc.w = fmaf(p_[u], bf2f(f_[u].w), acc.w);
            dsum += p_[u];
        }
    }
    for (; e < e1; ++e) {
        int s0 = csr_src[e];
        float e0 = as_[s0 * 4 + head] + ad;
        e0 = e0 > 0.f ? e0 : LRELU_SLOPE * e0;
        float p0 = __expf(e0);
        ushort4 u0 = *(const ushort4*)(h1 + (size_t)s0 * 256 + c0);
        acc.x = fmaf(p0, bf2f(u0.x), acc.x); acc.y = fmaf(p0, bf2f(u0.y), acc.y);
        acc.z = fmaf(p0, bf2f(u0.z), acc.z); acc.w = fmaf(p0, bf2f(u0.w), acc.w);
        dsum += p0;
    }
    const float inv = 1.f / (dsum + 1e-16f);
    const float4 b = *(const float4*)(bias + c0);
    float ox = acc.x * inv + b.x; ox = ox > 0.f ? ox : expm1f(ox);
    float oy = acc.y * inv + b.y; oy = oy > 0.f ? oy : expm1f(oy);
    float oz = acc.z * inv + b.z; oz = oz > 0.f ? oz : expm1f(oz);
    float ow = acc.w * inv + b.w; ow = ow > 0.f ? ow : expm1f(ow);
    ushort4 o;
    o.x = f2bf(ox); o.y = f2bf(oy); o.z = f2bf(oz); o.w = f2bf(ow);
    *(ushort4*)(outbf + (size_t)w * 256 + c0) = o;
}

// -------- layer-2 aggregation + scoring head; 8x unroll --------------------
__global__ __launch_bounds__(256)
void aggregate_l2(const int* __restrict__ rowptr, const int* __restrict__ csr_src,
                  const ushort* __restrict__ h2, const float* __restrict__ as_,
                  const float* __restrict__ ad_, const float* __restrict__ b2,
                  const float* __restrict__ Wsv, const float* __restrict__ bs,
                  float* __restrict__ hout, float* __restrict__ scores, int N)
{
    int w = (blockIdx.x * blockDim.x + threadIdx.x) >> 6;
    int lane = threadIdx.x & 63;
    if (w >= N) return;
    const float ad = ad_[w];
    float acc, dsum;
    {   // implicit self-loop
        float el = as_[w] + ad;
        el = el > 0.f ? el : LRELU_SLOPE * el;
        float p = __expf(el);
        acc = p * bf2f(h2[(size_t)w * 64 + lane]);
        dsum = p;
    }
    int e = rowptr[w];
    const int e1 = rowptr[w + 1];
    for (; e + 7 < e1; e += 8) {
        int s_[8];
        #pragma unroll
        for (int u = 0; u < 8; ++u) s_[u] = csr_src[e + u];
        float p_[8];
        #pragma unroll
        for (int u = 0; u < 8; ++u) {
            float ev = as_[s_[u]] + ad;
            ev = ev > 0.f ? ev : LRELU_SLOPE * ev;
            p_[u] = __expf(ev);
        }
        ushort f_[8];
        #pragma unroll
        for (int u = 0; u < 8; ++u) f_[u] = h2[(size_t)s_[u] * 64 + lane];
        #pragma unroll
        for (int u = 0; u < 8; ++u) {
            acc = fmaf(p_[u], bf2f(f_[u]), acc);
            dsum += p_[u];
        }
    }
    for (; e < e1; ++e) {
        int s0 = csr_src[e];
        float e0 = as_[s0] + ad;
        e0 = e0 > 0.f ? e0 : LRELU_SLOPE * e0;
        float p0 = __expf(e0);
        acc = fmaf(p0, bf2f(h2[(size_t)s0 * 64 + lane]), acc);
        dsum += p0;
    }
    float v = acc / (dsum + 1e-16f) + b2[lane];
    v = v > 0.f ? v : expm1f(v);
    hout[(size_t)w * 64 + lane] = v;
    float sc = v * Wsv[lane];
    #pragma unroll
    for (int off = 32; off; off >>= 1) sc += __shfl_down(sc, off);
    if (lane == 0) scores[w] = sc + bs[0];
}

// ---------------------------------------------------------------------------
extern "C" void kernel_launch(void* const* d_in, const int* in_sizes, int n_in,
                              void* d_out, int out_size, void* d_ws, size_t ws_size,
                              hipStream_t stream)
{
    const float* x    = (const float*)d_in[0];
    const int*   ei   = (const int*)d_in[1];
    const float* W1   = (const float*)d_in[2];
    const float* as1w = (const float*)d_in[3];
    const float* ad1w = (const float*)d_in[4];
    const float* b1   = (const float*)d_in[5];
    const float* W2   = (const float*)d_in[6];
    const float* as2w = (const float*)d_in[7];
    const float* ad2w = (const float*)d_in[8];
    const float* b2   = (const float*)d_in[9];
    const float* Ws   = (const float*)d_in[10];
    const float* bs   = (const float*)d_in[11];

    const int N  = in_sizes[0] / 128;   // 50000
    const int E  = in_sizes[1] / 2;     // 800000
    const int* esrc = ei;
    const int* edst = ei + E;

    // ---- workspace layout (16B-aligned chunks) ----
    ushort* h1bf  = (ushort*)d_ws;                       // N*256 bf16
    ushort* hl1bf = h1bf + (size_t)N * 256;              // N*256 bf16
    ushort* h2bf  = hl1bf + (size_t)N * 256;             // N*64 bf16
    ushort* xbf   = h2bf + (size_t)N * 64;               // N*128 bf16
    ushort* bfr1  = xbf + (size_t)N * 128;               // 32768
    ushort* bfr2  = bfr1 + 32768;                        // 16384
    float*  as1   = (float*)(bfr2 + 16384);              // N*4
    float*  ad1   = as1 + (size_t)N * 4;                 // N*4
    float*  as2   = ad1 + (size_t)N * 4;                 // N
    float*  ad2   = as2 + N;                             // N
    int*    deg    = (int*)(ad2 + N);                    // N
    int*    rowptr = deg + N;                            // N+1 (+pad)
    int*    csr_src= rowptr + N + 4;                     // E

    float* hout   = (float*)d_out;                       // N*64
    float* scores = hout + (size_t)N * 64;               // N

    // ---------------- CSR build (shared by both layers) ----------------
    hipMemsetAsync(deg, 0, (size_t)N * sizeof(int), stream);
    degree_hist<<<(E / 4 + 255) / 256, 256, 0, stream>>>(edst, deg, E);
    scan_rowptr<<<1, 1024, 0, stream>>>(deg, rowptr, N);
    scatter_edges<<<(E + 255) / 256, 256, 0, stream>>>(
        esrc, edst, rowptr, deg, csr_src, E);

    // ---------------- prep: x conversion + weight prefrag (one launch) --
    const int nconv4 = N * 128 / 4;
    prep<<<(nconv4 + 16 * 4 * 64 + 4 * 8 * 64 + 255) / 256, 256, 0, stream>>>(
        x, xbf, W1, W2, bfr1, bfr2, nconv4);

    // ---------------- layer 1 ----------------
    gemm_mfma<16, 4, 4><<<(N / 16 + 3) / 4, 256, 0, stream>>>(
        xbf, bfr1, h1bf, as1w, ad1w, as1, ad1, N);
    aggregate_l1<<<((size_t)N * 64 + 255) / 256, 256, 0, stream>>>(
        rowptr, csr_src, h1bf, as1, ad1, b1, hl1bf, N);

    // ---------------- layer 2 ----------------
    gemm_mfma<4, 8, 1><<<(N / 16 + 3) / 4, 256, 0, stream>>>(
        hl1bf, bfr2, h2bf, as2w, ad2w, as2, ad2, N);
    aggregate_l2<<<((size_t)N * 64 + 255) / 256, 256, 0, stream>>>(
        rowptr, csr_src, h2bf, as2, ad2, b2, Ws, bs, hout, scores, N);
}